// Round 12
// baseline (670.369 us; speedup 1.0000x reference)
//
#include <hip/hip_runtime.h>
#include <hip/hip_bf16.h>

#define NB 2048
#define NF 6144
#define ND 768
#define BM 256
#define BN 192
#define BK 32
#define SPLITK 2
#define KCH (NF / SPLITK)  // 3072 per block
#define NTIL (KCH / BK)    // 96 K-tiles per block

// LDS per buffer: A fp32 256 rows x 128 B = 32 KB ; B bf16 192 rows x 64 B = 12 KB
#define ABYTES (BM * BK * 4)
#define BBYTES (BN * BK * 2)
#define BUFB (ABYTES + BBYTES)  // 45056 ; tri-buffer = 132 KB

typedef __attribute__((ext_vector_type(4))) __bf16 bf16x4;
typedef __attribute__((ext_vector_type(8))) __bf16 bf16x8;
typedef __attribute__((ext_vector_type(4))) float f32x4;

// A (fp32, 128B rows, 8 x 16B slots): 3-bit swizzle, slot = kblk ^ fswz(row)
__device__ __forceinline__ int fswz(int r) { return ((r & 7) ^ ((r >> 2) & 7)) & 7; }
// B (bf16, 64B rows, 4 x 16B slots): 2-bit swizzle, slot = kblk ^ gswz(row)
// (bank-checked: DMA-write 2-way free; frag-read rows r0..r0+15 hit distinct
//  bank quads via (r&3)^((r>>2)&3) — 2-way = free)
__device__ __forceinline__ int gswz(int r) { return ((r & 3) ^ ((r >> 2) & 3)) & 3; }

__device__ __forceinline__ void async_ld16(void* lds, const void* g) {
  __builtin_amdgcn_global_load_lds(
      (const __attribute__((address_space(1))) void*)g,
      (__attribute__((address_space(3))) void*)lds, 16, 0, 0);
}

#define LGKM0()                                            \
  do {                                                     \
    asm volatile("s_waitcnt lgkmcnt(0)" ::: "memory");     \
    __builtin_amdgcn_sched_barrier(0);                     \
  } while (0)
#define VMW(N)                                             \
  do {                                                     \
    asm volatile("s_waitcnt vmcnt(" #N ")" ::: "memory");  \
    __builtin_amdgcn_sched_barrier(0);                     \
  } while (0)

// out[b,d] = sum_l bias[l,d]  (clears 0xAA poison deterministically)
__global__ __launch_bounds__(256) void bias_init_kernel(
    const float* __restrict__ bias, const int* __restrict__ lidx,
    float* __restrict__ out) {
  int n = lidx[0] + 1;
  int i = blockIdx.x * 256 + threadIdx.x;
  if (i >= NB * ND) return;
  int d = i % ND;
  float s = 0.f;
  for (int l = 0; l < n; ++l) s += bias[l * ND + d];
  out[i] = s;
}

// W[l][f][d] fp32 -> Wt[l][d][f] bf16 (64x64 LDS-tiled transpose; both global
// sides coalesced; LDS bank patterns 2-way max)
__global__ __launch_bounds__(256) void wt_kernel(
    const float* __restrict__ W, unsigned short* __restrict__ wt) {
  __shared__ float t[64][65];
  const int l = blockIdx.z, f0 = blockIdx.x * 64, d0 = blockIdx.y * 64;
  const int tid = threadIdx.x;
  const int fr = tid >> 4;          // 0..15
  const int dc4 = (tid & 15) * 4;   // 0..60
  const float* src = W + ((size_t)l * NF + f0 + fr) * ND + d0 + dc4;
#pragma unroll
  for (int i = 0; i < 4; ++i) {
    float4 v = *(const float4*)(src + (size_t)16 * i * ND);
    t[fr + 16 * i][dc4 + 0] = v.x;
    t[fr + 16 * i][dc4 + 1] = v.y;
    t[fr + 16 * i][dc4 + 2] = v.z;
    t[fr + 16 * i][dc4 + 3] = v.w;
  }
  __syncthreads();
  const int dr = tid >> 4;
  const int fc4 = (tid & 15) * 4;
  unsigned short* dst = wt + ((size_t)l * ND + d0 + dr) * NF + f0 + fc4;
#pragma unroll
  for (int i = 0; i < 4; ++i) {
    bf16x4 h;
    h[0] = (__bf16)t[fc4 + 0][dr + 16 * i];
    h[1] = (__bf16)t[fc4 + 1][dr + 16 * i];
    h[2] = (__bf16)t[fc4 + 2][dr + 16 * i];
    h[3] = (__bf16)t[fc4 + 3][dr + 16 * i];
    *(bf16x4*)(dst + (size_t)16 * i * NF) = h;
  }
}

// ---------------- main GEMM: ALL staging via global_load_lds ----------------
// 256x192, 8 waves (4m x 2n), BK=32, split-K x2, TRI-buffered LDS.
// Per tile, 2 dual-window phases (m201 template): {DMA issue || ds_read} ->
// BAR -> lgkm0 -> (cvt) -> setprio 12-MFMA -> BAR. A is fp32 in LDS,
// converted once per use in the MFMA window. DMA issued 2 tiles ahead;
// counted per-wave vmcnt(7/4) at the tile boundary (never 0 mid-loop).
__global__ __launch_bounds__(512, 2) void gemm_dma(
    const float* __restrict__ acts, const unsigned short* __restrict__ wt,
    const int* __restrict__ lidx, float* __restrict__ out, int nwg) {
  extern __shared__ char cbuf[];  // 3 * BUFB

  // by-fastest decode + XCD swizzle (R8: FETCH 1.27GB -> 405MB)
  const int chunk = nwg >> 3;  // 96
  const int swz = (blockIdx.x & 7) * chunk + (blockIdx.x >> 3);
  const int by = swz & 3;  // id = by + 4*(m + 8*(ks + 2*l))
  int rem = swz >> 2;
  const int m = rem & 7; rem >>= 3;
  const int ks = rem & 1; rem >>= 1;
  const int l = rem;
  if (l > lidx[0]) return;  // uniform exit before any barrier

  const int brow = m * BM;
  const int ncol = by * BN;
  const int k0 = ks * KCH;

  const int tid = threadIdx.x;
  const int lane = tid & 63;
  const int wid = tid >> 6;          // 8 waves: 4m x 2n
  const int wrow = (wid >> 1) * 64;  // 0,64,128,192
  const int wcol = (wid & 1) * 96;   // 0,96

  f32x4 acc[4][6];
#pragma unroll
  for (int i = 0; i < 4; ++i)
#pragma unroll
    for (int j = 0; j < 6; ++j) acc[i][j] = (f32x4){0.f, 0.f, 0.f, 0.f};

  // --- DMA descriptors (fixed per thread; advance by t*BK elems) ---
  // A: wave w issues 4 instrs, instr j covers rows 8*(4w+j)..+7, lane ->
  // (row = r0+lane>>3, slot = lane&7); source k-block = slot ^ fswz(row)
  const float* aSrc[4];
  int aDst[4];
#pragma unroll
  for (int j = 0; j < 4; ++j) {
    const int r0 = 8 * (4 * wid + j);
    const int r = r0 + (lane >> 3);
    const int ksl = (lane & 7) ^ fswz(r);
    aSrc[j] = acts + ((size_t)l * NB + brow + r) * NF + k0 + ksl * 4;
    aDst[j] = r0 * 128;
  }
  // B: waves 0-3 issue 3 instrs each; instr i covers rows 16*i..+15, lane ->
  // (row = r0+lane>>2, slot = lane&3); source k-block = slot ^ gswz(row)
  const bool bwave = (wid < 4);
  const unsigned short* bSrc[3];
  int bDst[3];
#pragma unroll
  for (int j = 0; j < 3; ++j) {
    const int i = 3 * (wid & 3) + j;
    const int r0 = 16 * i;
    const int r = r0 + (lane >> 2);
    const int ksl = (lane & 3) ^ gswz(r);
    bSrc[j] = wt + ((size_t)l * ND + ncol + r) * NF + k0 + ksl * 8;
    bDst[j] = ABYTES + r0 * 64;
  }

  auto DMA_A = [&](int t, int buf) {
    char* b = cbuf + (size_t)buf * BUFB;
#pragma unroll
    for (int j = 0; j < 4; ++j) async_ld16(b + aDst[j], aSrc[j] + (size_t)t * BK);
  };
  auto DMA_B = [&](int t, int buf) {
    if (bwave) {
      char* b = cbuf + (size_t)buf * BUFB;
#pragma unroll
      for (int j = 0; j < 3; ++j) async_ld16(b + bDst[j], bSrc[j] + (size_t)t * BK);
    }
  };

  const int kq = lane >> 4;  // k-quarter 0..3 (kk = kq*8)

  // ---- prologue: tiles 0,1 in flight; wait tile 0 (counted) ----
  DMA_A(0, 0); DMA_B(0, 0);
  DMA_A(1, 1); DMA_B(1, 1);
  if (bwave) { VMW(7); } else { VMW(4); }
  __builtin_amdgcn_s_barrier();
  __builtin_amdgcn_sched_barrier(0);

  for (int t = 0; t < NTIL; ++t) {
    char* bA = cbuf + (size_t)(t % 3) * BUFB;
    char* bB = bA + ABYTES;
    const int nb = (t + 2) % 3;
    const bool more = (t + 2 < NTIL);

    // ======== phase 0: DMA_A(t+2) || read aF(f32) + bF0..2 ========
    if (more) DMA_A(t + 2, nb);
    float4 aLo[4], aHi[4];
#pragma unroll
    for (int mi = 0; mi < 4; ++mi) {
      const int r = wrow + mi * 16 + (lane & 15);
      const int sl = ((kq * 2) ^ fswz(r)) & 7;  // kblk even -> +1 == ^1
      aLo[mi] = *(const float4*)(bA + r * 128 + sl * 16);
      aHi[mi] = *(const float4*)(bA + r * 128 + (sl ^ 1) * 16);
    }
    bf16x8 bF0[3];
#pragma unroll
    for (int ni = 0; ni < 3; ++ni) {
      const int r = wcol + ni * 16 + (lane & 15);
      const int s2 = (kq ^ gswz(r)) & 3;
      bF0[ni] = *(const bf16x8*)(bB + r * 64 + s2 * 16);
    }
    __builtin_amdgcn_s_barrier();
    LGKM0();
    bf16x8 aF[4];
#pragma unroll
    for (int mi = 0; mi < 4; ++mi) {
      bf16x8 h;
      h[0] = (__bf16)aLo[mi].x; h[1] = (__bf16)aLo[mi].y;
      h[2] = (__bf16)aLo[mi].z; h[3] = (__bf16)aLo[mi].w;
      h[4] = (__bf16)aHi[mi].x; h[5] = (__bf16)aHi[mi].y;
      h[6] = (__bf16)aHi[mi].z; h[7] = (__bf16)aHi[mi].w;
      aF[mi] = h;
    }
    __builtin_amdgcn_s_setprio(1);
#pragma unroll
    for (int mi = 0; mi < 4; ++mi)
#pragma unroll
      for (int ni = 0; ni < 3; ++ni)
        acc[mi][ni] = __builtin_amdgcn_mfma_f32_16x16x32_bf16(
            aF[mi], bF0[ni], acc[mi][ni], 0, 0, 0);
    __builtin_amdgcn_s_setprio(0);
    __builtin_amdgcn_sched_barrier(0);
    __builtin_amdgcn_s_barrier();

    // ======== phase 1: DMA_B(t+2) || read bF3..5 ========
    if (more) DMA_B(t + 2, nb);
    bf16x8 bF1[3];
#pragma unroll
    for (int ni = 0; ni < 3; ++ni) {
      const int r = wcol + (3 + ni) * 16 + (lane & 15);
      const int s2 = (kq ^ gswz(r)) & 3;
      bF1[ni] = *(const bf16x8*)(bB + r * 64 + s2 * 16);
    }
    __builtin_amdgcn_s_barrier();
    LGKM0();
    __builtin_amdgcn_s_setprio(1);
#pragma unroll
    for (int mi = 0; mi < 4; ++mi)
#pragma unroll
      for (int ni = 0; ni < 3; ++ni)
        acc[mi][3 + ni] = __builtin_amdgcn_mfma_f32_16x16x32_bf16(
            aF[mi], bF1[ni], acc[mi][3 + ni], 0, 0, 0);
    __builtin_amdgcn_s_setprio(0);
    __builtin_amdgcn_sched_barrier(0);

    // tile boundary: ensure DMA(t+1) (issued last tile) landed. Counted:
    // outstanding <= own issues THIS tile (7 bwave / 4 other) => all older
    // (incl. every DMA(t+1)) retired. Endgame (no issues this tile): 0.
    if (more) {
      if (bwave) { VMW(7); } else { VMW(4); }
    } else {
      VMW(0);
    }
    __builtin_amdgcn_s_barrier();
    __builtin_amdgcn_sched_barrier(0);
  }

  // ---- epilogue: atomic accumulate (24 blocks collide: 12L x 2K) ----
  // C/D layout (m89-verified): col = lane&15, row = (lane>>4)*4 + j
  const int orow = brow + wrow + ((lane >> 4) << 2);
  const int ocol = ncol + wcol + (lane & 15);
#pragma unroll
  for (int mi = 0; mi < 4; ++mi)
#pragma unroll
    for (int ni = 0; ni < 6; ++ni)
#pragma unroll
      for (int j = 0; j < 4; ++j)
        atomicAdd(out + (size_t)(orow + mi * 16 + j) * ND + (ocol + ni * 16),
                  acc[mi][ni][j]);
}

// ---------------- fallback (ws too small): R8 fused kernel ----------------
#define F_BK 64
#define F_NTIL 48
#define F_AB 32768
#define F_BUF 57344
__device__ __forceinline__ char* lds_fb(char* base, int row, int k) {
  const int blk = ((k >> 3) ^ fswz(row)) & 7;
  return base + row * 128 + (blk << 4) + ((k & 7) << 1);
}
__global__ __launch_bounds__(512, 2) void gemm_fused(
    const float* __restrict__ acts, const float* __restrict__ W,
    const int* __restrict__ lidx, float* __restrict__ out, int nwg) {
  extern __shared__ char cbuf[];
  const int chunk = nwg >> 3;
  const int swz = (blockIdx.x & 7) * chunk + (blockIdx.x >> 3);
  const int by = swz & 3;
  int rem = swz >> 2;
  const int m = rem & 7; rem >>= 3;
  const int ks = rem & 1; rem >>= 1;
  const int l = rem;
  if (l > lidx[0]) return;
  const int brow = m * BM, ncol = by * BN, k0 = ks * KCH;
  const int tid = threadIdx.x, lane = tid & 63, wid = tid >> 6;
  const int wrow = (wid >> 1) * 64, wcol = (wid & 1) * 96;
  f32x4 acc[4][6];
#pragma unroll
  for (int i = 0; i < 4; ++i)
#pragma unroll
    for (int j = 0; j < 6; ++j) acc[i][j] = (f32x4){0.f, 0.f, 0.f, 0.f};
  const int s_arow = tid >> 3, s_ak = (tid & 7) * 8;
  const bool bstage = tid < 384;
  const int s_bd = (tid % 48) * 4, s_bk = (tid / 48) * 8;
  const float* Aptr =
      acts + (size_t)l * NB * NF + (size_t)(brow + s_arow) * NF + k0 + s_ak;
  const float* Bptr =
      W + (size_t)l * NF * ND + (size_t)(k0 + s_bk) * ND + (ncol + s_bd);
  float4 av[4][2]; float4 bv[8];
  auto LOADS = [&](int kb) {
#pragma unroll
    for (int p = 0; p < 4; ++p) {
      av[p][0] = *(const float4*)(Aptr + (size_t)(64 * p) * NF + kb);
      av[p][1] = *(const float4*)(Aptr + (size_t)(64 * p) * NF + kb + 4);
    }
    if (bstage) {
#pragma unroll
      for (int j = 0; j < 8; ++j)
        bv[j] = *(const float4*)(Bptr + (size_t)(kb + j) * ND);
    }
  };
  auto STORE = [&](char* cA_, char* cB_) {
#pragma unroll
    for (int p = 0; p < 4; ++p) {
      bf16x8 h;
      h[0] = (__bf16)av[p][0].x; h[1] = (__bf16)av[p][0].y;
      h[2] = (__bf16)av[p][0].z; h[3] = (__bf16)av[p][0].w;
      h[4] = (__bf16)av[p][1].x; h[5] = (__bf16)av[p][1].y;
      h[6] = (__bf16)av[p][1].z; h[7] = (__bf16)av[p][1].w;
      *(bf16x8*)lds_fb(cA_, s_arow + 64 * p, s_ak) = h;
    }
    if (bstage) {
#pragma unroll
      for (int dd = 0; dd < 4; ++dd) {
        bf16x8 h;
#pragma unroll
        for (int j = 0; j < 8; ++j) h[j] = (__bf16)bv[j][dd];
        *(bf16x8*)lds_fb(cB_, s_bd + dd, s_bk) = h;
      }
    }
  };
  LOADS(0);
  STORE(cbuf, cbuf + F_AB);
  for (int t = 0; t < F_NTIL; ++t) {
    const int cur = t & 1;
    char* rA = cbuf + (size_t)cur * F_BUF;
    char* rB = rA + F_AB;
    char* wA = cbuf + (size_t)(cur ^ 1) * F_BUF;
    char* wB = wA + F_AB;
    LGKM0();
    __builtin_amdgcn_s_barrier();
    __builtin_amdgcn_sched_barrier(0);
    if (t + 1 < F_NTIL) LOADS((t + 1) * F_BK);
    __builtin_amdgcn_sched_barrier(0);
    bf16x8 aF[4][2];
#pragma unroll
    for (int mi = 0; mi < 4; ++mi)
#pragma unroll
      for (int s = 0; s < 2; ++s)
        aF[mi][s] = *(const bf16x8*)lds_fb(
            rA, wrow + mi * 16 + (lane & 15), s * 32 + (lane >> 4) * 8);
#pragma unroll
    for (int p = 0; p < 3; ++p) {
      bf16x8 bF[2][2];
#pragma unroll
      for (int ni = 0; ni < 2; ++ni)
#pragma unroll
        for (int s = 0; s < 2; ++s)
          bF[ni][s] = *(const bf16x8*)lds_fb(
              rB, wcol + (2 * p + ni) * 16 + (lane & 15),
              s * 32 + (lane >> 4) * 8);
      LGKM0();
      __builtin_amdgcn_s_setprio(1);
#pragma unroll
      for (int s = 0; s < 2; ++s)
#pragma unroll
        for (int mi = 0; mi < 4; ++mi)
#pragma unroll
          for (int ni = 0; ni < 2; ++ni)
            acc[mi][2 * p + ni] = __builtin_amdgcn_mfma_f32_16x16x32_bf16(
                aF[mi][s], bF[ni][s], acc[mi][2 * p + ni], 0, 0, 0);
      __builtin_amdgcn_s_setprio(0);
      __builtin_amdgcn_sched_barrier(0);
    }
    if (t + 1 < F_NTIL) STORE(wA, wB);
  }
  const int orow = brow + wrow + ((lane >> 4) << 2);
  const int ocol = ncol + wcol + (lane & 15);
#pragma unroll
  for (int mi = 0; mi < 4; ++mi)
#pragma unroll
    for (int ni = 0; ni < 6; ++ni)
#pragma unroll
      for (int j = 0; j < 4; ++j)
        atomicAdd(out + (size_t)(orow + mi * 16 + j) * ND + (ocol + ni * 16),
                  acc[mi][ni][j]);
}

extern "C" void kernel_launch(void* const* d_in, const int* in_sizes, int n_in,
                              void* d_out, int out_size, void* d_ws, size_t ws_size,
                              hipStream_t stream) {
  const float* acts = (const float*)d_in[0];
  const float* W    = (const float*)d_in[1];
  const float* bias = (const float*)d_in[2];
  const int*   lidx = (const int*)d_in[3];
  float* out = (float*)d_out;

  const int L = in_sizes[0] / (NB * NF);               // 12
  const int nwg = (ND / BN) * (NB / BM) * SPLITK * L;  // 768 = 3 x 256 CUs
  const size_t wsNeed = (size_t)L * NF * ND * 2;       // 113 MB bf16 W^T

  bias_init_kernel<<<dim3((NB * ND + 255) / 256), 256, 0, stream>>>(bias, lidx, out);

  if (ws_size >= wsNeed) {
    unsigned short* wsB = (unsigned short*)d_ws;
    wt_kernel<<<dim3(NF / 64, ND / 64, L), 256, 0, stream>>>(W, wsB);
    hipFuncSetAttribute((const void*)gemm_dma,
                        hipFuncAttributeMaxDynamicSharedMemorySize, 3 * BUFB);
    gemm_dma<<<dim3(nwg), 512, 3 * BUFB, stream>>>(acts, wsB, lidx, out, nwg);
  } else {
    hipFuncSetAttribute((const void*)gemm_fused,
                        hipFuncAttributeMaxDynamicSharedMemorySize, 2 * F_BUF);
    gemm_fused<<<dim3(nwg), 512, 2 * F_BUF, stream>>>(acts, W, lidx, out, nwg);
  }
}

// Round 13
// 542.732 us; speedup vs baseline: 1.2352x; 1.2352x over previous
//
#include <hip/hip_runtime.h>
#include <hip/hip_bf16.h>

#define NB 2048
#define NF 6144
#define ND 768
#define BM 256
#define BN 192
#define BK 64
#define SPLITK 2
#define KCH (NF / SPLITK)  // 3072 per block
#define NTIL (KCH / BK)    // 48 K-tiles per block

// LDS per buffer: A bf16 256 rows x 128 B = 32 KB; B bf16 192 rows x 128 B = 24 KB
#define ABYTES (BM * 128)
#define BBYTES (BN * 128)
#define BUFB (ABYTES + BBYTES)  // 57344; dbuf = 112 KB

typedef __attribute__((ext_vector_type(4))) __bf16 bf16x4;
typedef __attribute__((ext_vector_type(8))) __bf16 bf16x8;
typedef __attribute__((ext_vector_type(4))) float f32x4;

// THE proven layout (0 conflicts, rounds 2-4,6-11): 128B rows of 64 bf16,
// 16B-slot 3-bit swizzle slot = (k>>3) ^ fswz(row).
__device__ __forceinline__ int fswz(int r) { return ((r & 7) ^ ((r >> 2) & 7)) & 7; }
__device__ __forceinline__ char* lds_addr(char* base, int row, int k) {
  const int blk = ((k >> 3) ^ fswz(row)) & 7;
  return base + row * 128 + (blk << 4) + ((k & 7) << 1);
}

__device__ __forceinline__ void async_ld16(void* lds, const void* g) {
  __builtin_amdgcn_global_load_lds(
      (const __attribute__((address_space(1))) void*)g,
      (__attribute__((address_space(3))) void*)lds, 16, 0, 0);
}

#define SBAR0() __builtin_amdgcn_sched_barrier(0)
#define LGKM(N)                                              \
  do {                                                       \
    asm volatile("s_waitcnt lgkmcnt(" #N ")" ::: "memory");  \
    SBAR0();                                                 \
  } while (0)
#define VMW(N)                                               \
  do {                                                       \
    asm volatile("s_waitcnt vmcnt(" #N ")" ::: "memory");    \
    SBAR0();                                                 \
  } while (0)

// out[b,d] = sum_l bias[l,d]  (clears 0xAA poison deterministically)
__global__ __launch_bounds__(256) void bias_init_kernel(
    const float* __restrict__ bias, const int* __restrict__ lidx,
    float* __restrict__ out) {
  int n = lidx[0] + 1;
  int i = blockIdx.x * 256 + threadIdx.x;
  if (i >= NB * ND) return;
  int d = i % ND;
  float s = 0.f;
  for (int l = 0; l < n; ++l) s += bias[l * ND + d];
  out[i] = s;
}

// W[l][f][d] fp32 -> Wt[l][d][f] bf16 (R12-verified, ~48us)
__global__ __launch_bounds__(256) void wt_kernel(
    const float* __restrict__ W, unsigned short* __restrict__ wt) {
  __shared__ float t[64][65];
  const int l = blockIdx.z, f0 = blockIdx.x * 64, d0 = blockIdx.y * 64;
  const int tid = threadIdx.x;
  const int fr = tid >> 4;
  const int dc4 = (tid & 15) * 4;
  const float* src = W + ((size_t)l * NF + f0 + fr) * ND + d0 + dc4;
#pragma unroll
  for (int i = 0; i < 4; ++i) {
    float4 v = *(const float4*)(src + (size_t)16 * i * ND);
    t[fr + 16 * i][dc4 + 0] = v.x;
    t[fr + 16 * i][dc4 + 1] = v.y;
    t[fr + 16 * i][dc4 + 2] = v.z;
    t[fr + 16 * i][dc4 + 3] = v.w;
  }
  __syncthreads();
  const int dr = tid >> 4;
  const int fc4 = (tid & 15) * 4;
  unsigned short* dst = wt + ((size_t)l * ND + d0 + dr) * NF + f0 + fc4;
#pragma unroll
  for (int i = 0; i < 4; ++i) {
    bf16x4 h;
    h[0] = (__bf16)t[fc4 + 0][dr + 16 * i];
    h[1] = (__bf16)t[fc4 + 1][dr + 16 * i];
    h[2] = (__bf16)t[fc4 + 2][dr + 16 * i];
    h[3] = (__bf16)t[fc4 + 3][dr + 16 * i];
    *(bf16x4*)(dst + (size_t)16 * i * NF) = h;
  }
}

// ---------------- main GEMM ----------------
// R8 base (256x192, 8 waves 4m x 2n, BK64, dbuf, 1 barrier/tile) +
// (1) B staged via global_load_lds from bf16 W^T (R10-proven DMA pattern),
// (2) fragment software-pipeline: bF pair p+1 in flight (counted lgkmcnt(4))
//     under MFMA cluster p, (3) A fused fp32 reg-stage (unchanged).
__global__ __launch_bounds__(512, 2) void gemm_dma(
    const float* __restrict__ acts, const unsigned short* __restrict__ wt,
    const int* __restrict__ lidx, float* __restrict__ out, int nwg) {
  extern __shared__ char cbuf[];  // 2 * BUFB

  // by-fastest decode + XCD swizzle (R8: FETCH 1.27GB -> 405MB)
  const int chunk = nwg >> 3;  // 96
  const int swz = (blockIdx.x & 7) * chunk + (blockIdx.x >> 3);
  const int by = swz & 3;  // id = by + 4*(m + 8*(ks + 2*l))
  int rem = swz >> 2;
  const int m = rem & 7; rem >>= 3;
  const int ks = rem & 1; rem >>= 1;
  const int l = rem;
  if (l > lidx[0]) return;  // uniform exit before any barrier

  const int brow = m * BM;
  const int ncol = by * BN;
  const int k0 = ks * KCH;

  const int tid = threadIdx.x;
  const int lane = tid & 63;
  const int wid = tid >> 6;          // 8 waves: 4m x 2n
  const int wrow = (wid >> 1) * 64;  // 0,64,128,192
  const int wcol = (wid & 1) * 96;   // 0,96

  f32x4 acc[4][6];
#pragma unroll
  for (int i = 0; i < 4; ++i)
#pragma unroll
    for (int j = 0; j < 6; ++j) acc[i][j] = (f32x4){0.f, 0.f, 0.f, 0.f};

  // A reg-staging (R8): thread -> (row = tid>>3 (+64 per p), 8 consecutive k)
  const int s_arow = tid >> 3;
  const int s_ak = (tid & 7) * 8;
  const float* Aptr =
      acts + (size_t)l * NB * NF + (size_t)(brow + s_arow) * NF + k0 + s_ak;
  float4 av[4][2];

  // B DMA (R10-proven pattern): wave w, instr j covers rows r0=8*(3w+j);
  // lane -> row r0+(lane>>3), slot lane&7; global k-block = slot ^ fswz(r).
  const unsigned short* bSrc[3];
  int bDst[3];
#pragma unroll
  for (int j = 0; j < 3; ++j) {
    const int r0 = 8 * (3 * wid + j);
    const int r = r0 + (lane >> 3);
    const int ksl = (lane & 7) ^ fswz(r);
    bSrc[j] = wt + ((size_t)l * ND + ncol + r) * NF + k0 + ksl * 8;
    bDst[j] = ABYTES + r0 * 128;
  }

  auto ALOADS = [&](int kb) {
#pragma unroll
    for (int p = 0; p < 4; ++p) {
      av[p][0] = *(const float4*)(Aptr + (size_t)(64 * p) * NF + kb);
      av[p][1] = *(const float4*)(Aptr + (size_t)(64 * p) * NF + kb + 4);
    }
  };
  auto DMA_B = [&](int t, int buf) {
    char* b = cbuf + (size_t)buf * BUFB;
#pragma unroll
    for (int j = 0; j < 3; ++j)
      async_ld16(b + bDst[j], bSrc[j] + (size_t)t * BK);
  };
  auto ASTORE = [&](char* cA_) {  // cvt + swizzled ds_write (vmcnt dep on av)
#pragma unroll
    for (int p = 0; p < 4; ++p) {
      bf16x8 h;
      h[0] = (__bf16)av[p][0].x; h[1] = (__bf16)av[p][0].y;
      h[2] = (__bf16)av[p][0].z; h[3] = (__bf16)av[p][0].w;
      h[4] = (__bf16)av[p][1].x; h[5] = (__bf16)av[p][1].y;
      h[6] = (__bf16)av[p][1].z; h[7] = (__bf16)av[p][1].w;
      *(bf16x8*)lds_addr(cA_, s_arow + 64 * p, s_ak) = h;
    }
  };

// Read one bF pair P (4 x ds_read_b128) into named regs.
#define BF_READ(dst, P)                                                   \
  _Pragma("unroll") for (int ni = 0; ni < 2; ++ni)                        \
    _Pragma("unroll") for (int s = 0; s < 2; ++s)                         \
      dst[ni][s] = *(const bf16x8*)lds_addr(                              \
          rB, wcol + (2 * (P) + ni) * 16 + (lane & 15),                   \
          s * 32 + (lane >> 4) * 8);

#define MFMA16(bf, P)                                                     \
  __builtin_amdgcn_s_setprio(1);                                          \
  _Pragma("unroll") for (int s = 0; s < 2; ++s)                           \
    _Pragma("unroll") for (int mi = 0; mi < 4; ++mi)                      \
      _Pragma("unroll") for (int ni = 0; ni < 2; ++ni)                    \
        acc[mi][2 * (P) + ni] = __builtin_amdgcn_mfma_f32_16x16x32_bf16(  \
            aF[mi][s], bf[ni][s], acc[mi][2 * (P) + ni], 0, 0, 0);        \
  __builtin_amdgcn_s_setprio(0);                                          \
  SBAR0();

  // ---- prologue: stage tile 0 only (serial, once) ----
  ALOADS(0);
  DMA_B(0, 0);
  ASTORE(cbuf);   // reg-dep waits own av
  VMW(0);         // DMA_B(0) landed
  LGKM(0);        // A writes drained
  // loop-top barrier publishes

  for (int t = 0; t < NTIL; ++t) {
    const int cur = t & 1;
    char* rA = cbuf + (size_t)cur * BUFB;
    char* rB = rA + ABYTES;
    char* wA = cbuf + (size_t)(cur ^ 1) * BUFB;
    const bool more = (t + 1 < NTIL);

    __builtin_amdgcn_s_barrier();  // publish: A(t),B(t) in buf[cur]
    SBAR0();

    // issue next tile's staging: av loads first, then DMA (so av's reg-dep
    // wait in ASTORE leaves the 3 DMAs outstanding)
    if (more) {
      ALOADS((t + 1) * BK);
      DMA_B(t + 1, cur ^ 1);
    }
    SBAR0();

    // ---- fragment pipeline: aF + bF0 + bF1 issued; wait 12 oldest ----
    bf16x8 aF[4][2];
#pragma unroll
    for (int mi = 0; mi < 4; ++mi)
#pragma unroll
      for (int s = 0; s < 2; ++s)
        aF[mi][s] = *(const bf16x8*)lds_addr(
            rA, wrow + mi * 16 + (lane & 15), s * 32 + (lane >> 4) * 8);
    bf16x8 bFa[2][2], bFb[2][2], bFc[2][2];
    BF_READ(bFa, 0)
    BF_READ(bFb, 1)
    SBAR0();
    LGKM(4);        // aF + bFa landed; bFb (4) still in flight
    MFMA16(bFa, 0)

    BF_READ(bFc, 2) // in flight under P1
    SBAR0();
    LGKM(4);        // bFb landed
    MFMA16(bFb, 1)

    LGKM(0);        // bFc landed
    MFMA16(bFc, 2)

    // ---- stage writes for t+1 (av loads are ~3 MFMA phases old) ----
    if (more) ASTORE(wA);
    VMW(0);         // own DMA_B(t+1) landed (issued a full tile ago)
    LGKM(0);        // A(t+1) ds_writes drained
  }

#undef BF_READ
#undef MFMA16

  // ---- epilogue: atomic accumulate (24 blocks collide: 12L x 2K) ----
  // C/D layout (m89-verified): col = lane&15, row = (lane>>4)*4 + j
  const int orow = brow + wrow + ((lane >> 4) << 2);
  const int ocol = ncol + wcol + (lane & 15);
#pragma unroll
  for (int mi = 0; mi < 4; ++mi)
#pragma unroll
    for (int ni = 0; ni < 6; ++ni)
#pragma unroll
      for (int j = 0; j < 4; ++j)
        atomicAdd(out + (size_t)(orow + mi * 16 + j) * ND + (ocol + ni * 16),
                  acc[mi][ni][j]);
}

// ---------------- fallback (ws too small): R8 fused kernel (475us) ----------
__global__ __launch_bounds__(512, 2) void gemm_fused(
    const float* __restrict__ acts, const float* __restrict__ W,
    const int* __restrict__ lidx, float* __restrict__ out, int nwg) {
  extern __shared__ char cbuf[];
  const int chunk = nwg >> 3;
  const int swz = (blockIdx.x & 7) * chunk + (blockIdx.x >> 3);
  const int by = swz & 3;
  int rem = swz >> 2;
  const int m = rem & 7; rem >>= 3;
  const int ks = rem & 1; rem >>= 1;
  const int l = rem;
  if (l > lidx[0]) return;
  const int brow = m * BM, ncol = by * BN, k0 = ks * KCH;
  const int tid = threadIdx.x, lane = tid & 63, wid = tid >> 6;
  const int wrow = (wid >> 1) * 64, wcol = (wid & 1) * 96;
  f32x4 acc[4][6];
#pragma unroll
  for (int i = 0; i < 4; ++i)
#pragma unroll
    for (int j = 0; j < 6; ++j) acc[i][j] = (f32x4){0.f, 0.f, 0.f, 0.f};
  const int s_arow = tid >> 3, s_ak = (tid & 7) * 8;
  const bool bstage = tid < 384;
  const int s_bd = (tid % 48) * 4, s_bk = (tid / 48) * 8;
  const float* Aptr =
      acts + (size_t)l * NB * NF + (size_t)(brow + s_arow) * NF + k0 + s_ak;
  const float* Bptr =
      W + (size_t)l * NF * ND + (size_t)(k0 + s_bk) * ND + (ncol + s_bd);
  float4 av[4][2]; float4 bv[8];
  auto LOADS = [&](int kb) {
#pragma unroll
    for (int p = 0; p < 4; ++p) {
      av[p][0] = *(const float4*)(Aptr + (size_t)(64 * p) * NF + kb);
      av[p][1] = *(const float4*)(Aptr + (size_t)(64 * p) * NF + kb + 4);
    }
    if (bstage) {
#pragma unroll
      for (int j = 0; j < 8; ++j)
        bv[j] = *(const float4*)(Bptr + (size_t)(kb + j) * ND);
    }
  };
  auto STORE = [&](char* cA_, char* cB_) {
#pragma unroll
    for (int p = 0; p < 4; ++p) {
      bf16x8 h;
      h[0] = (__bf16)av[p][0].x; h[1] = (__bf16)av[p][0].y;
      h[2] = (__bf16)av[p][0].z; h[3] = (__bf16)av[p][0].w;
      h[4] = (__bf16)av[p][1].x; h[5] = (__bf16)av[p][1].y;
      h[6] = (__bf16)av[p][1].z; h[7] = (__bf16)av[p][1].w;
      *(bf16x8*)lds_addr(cA_, s_arow + 64 * p, s_ak) = h;
    }
    if (bstage) {
#pragma unroll
      for (int dd = 0; dd < 4; ++dd) {
        bf16x8 h;
#pragma unroll
        for (int j = 0; j < 8; ++j) h[j] = (__bf16)bv[j][dd];
        *(bf16x8*)lds_addr(cB_, s_bd + dd, s_bk) = h;
      }
    }
  };
  LOADS(0);
  STORE(cbuf, cbuf + ABYTES);
  for (int t = 0; t < NTIL; ++t) {
    const int cur = t & 1;
    char* rA = cbuf + (size_t)cur * BUFB;
    char* rB = rA + ABYTES;
    char* wA = cbuf + (size_t)(cur ^ 1) * BUFB;
    char* wB = wA + ABYTES;
    LGKM(0);
    __builtin_amdgcn_s_barrier();
    SBAR0();
    if (t + 1 < NTIL) LOADS((t + 1) * BK);
    SBAR0();
    bf16x8 aF[4][2];
#pragma unroll
    for (int mi = 0; mi < 4; ++mi)
#pragma unroll
      for (int s = 0; s < 2; ++s)
        aF[mi][s] = *(const bf16x8*)lds_addr(
            rA, wrow + mi * 16 + (lane & 15), s * 32 + (lane >> 4) * 8);
#pragma unroll
    for (int p = 0; p < 3; ++p) {
      bf16x8 bF[2][2];
#pragma unroll
      for (int ni = 0; ni < 2; ++ni)
#pragma unroll
        for (int s = 0; s < 2; ++s)
          bF[ni][s] = *(const bf16x8*)lds_addr(
              rB, wcol + (2 * p + ni) * 16 + (lane & 15),
              s * 32 + (lane >> 4) * 8);
      LGKM(0);
      __builtin_amdgcn_s_setprio(1);
#pragma unroll
      for (int s = 0; s < 2; ++s)
#pragma unroll
        for (int mi = 0; mi < 4; ++mi)
#pragma unroll
          for (int ni = 0; ni < 2; ++ni)
            acc[mi][2 * p + ni] = __builtin_amdgcn_mfma_f32_16x16x32_bf16(
                aF[mi][s], bF[ni][s], acc[mi][2 * p + ni], 0, 0, 0);
      __builtin_amdgcn_s_setprio(0);
      SBAR0();
    }
    if (t + 1 < NTIL) STORE(wA, wB);
  }
  const int orow = brow + wrow + ((lane >> 4) << 2);
  const int ocol = ncol + wcol + (lane & 15);
#pragma unroll
  for (int mi = 0; mi < 4; ++mi)
#pragma unroll
    for (int ni = 0; ni < 6; ++ni)
#pragma unroll
      for (int j = 0; j < 4; ++j)
        atomicAdd(out + (size_t)(orow + mi * 16 + j) * ND + (ocol + ni * 16),
                  acc[mi][ni][j]);
}

extern "C" void kernel_launch(void* const* d_in, const int* in_sizes, int n_in,
                              void* d_out, int out_size, void* d_ws, size_t ws_size,
                              hipStream_t stream) {
  const float* acts = (const float*)d_in[0];
  const float* W    = (const float*)d_in[1];
  const float* bias = (const float*)d_in[2];
  const int*   lidx = (const int*)d_in[3];
  float* out = (float*)d_out;

  const int L = in_sizes[0] / (NB * NF);               // 12
  const int nwg = (ND / BN) * (NB / BM) * SPLITK * L;  // 768 = 3 x 256 CUs
  const size_t wsNeed = (size_t)L * NF * ND * 2;       // 113 MB bf16 W^T

  bias_init_kernel<<<dim3((NB * ND + 255) / 256), 256, 0, stream>>>(bias, lidx, out);

  if (ws_size >= wsNeed) {
    unsigned short* wsB = (unsigned short*)d_ws;
    wt_kernel<<<dim3(NF / 64, ND / 64, L), 256, 0, stream>>>(W, wsB);
    hipFuncSetAttribute((const void*)gemm_dma,
                        hipFuncAttributeMaxDynamicSharedMemorySize, 2 * BUFB);
    gemm_dma<<<dim3(nwg), 512, 2 * BUFB, stream>>>(acts, wsB, lidx, out, nwg);
  } else {
    hipFuncSetAttribute((const void*)gemm_fused,
                        hipFuncAttributeMaxDynamicSharedMemorySize, 2 * BUFB);
    gemm_fused<<<dim3(nwg), 512, 2 * BUFB, stream>>>(acts, W, lidx, out, nwg);
  }
}

// Round 14
// 498.282 us; speedup vs baseline: 1.3454x; 1.0892x over previous
//
#include <hip/hip_runtime.h>
#include <hip/hip_bf16.h>

#define NB 2048
#define NF 6144
#define ND 768
#define BM 256
#define BN 192
#define BK 64
#define SPLITK 2
#define KCH (NF / SPLITK)  // 3072 per block
#define NTIL (KCH / BK)    // 48 K-tiles per block

// LDS: A dbuf 2 x 32 KB (bf16) | B tri-buf 3 x 24 KB (bf16) = 136 KB
#define A_BYTES (BM * 128)
#define B_BYTES (BN * 128)
#define BBUF_OFF (2 * A_BYTES)
#define LDS_TOTAL (2 * A_BYTES + 3 * B_BYTES)  // 139264

typedef __attribute__((ext_vector_type(4))) __bf16 bf16x4;
typedef __attribute__((ext_vector_type(8))) __bf16 bf16x8;
typedef __attribute__((ext_vector_type(4))) float f32x4;

// THE proven layout (0 conflicts, rounds 2-13): 128B rows of 64 bf16,
// 16B-slot 3-bit swizzle slot = (k>>3) ^ fswz(row).
__device__ __forceinline__ int fswz(int r) { return ((r & 7) ^ ((r >> 2) & 7)) & 7; }
__device__ __forceinline__ char* lds_addr(char* base, int row, int k) {
  const int blk = ((k >> 3) ^ fswz(row)) & 7;
  return base + row * 128 + (blk << 4) + ((k & 7) << 1);
}

__device__ __forceinline__ void async_ld16(void* lds, const void* g) {
  __builtin_amdgcn_global_load_lds(
      (const __attribute__((address_space(1))) void*)g,
      (__attribute__((address_space(3))) void*)lds, 16, 0, 0);
}

#define SBAR0() __builtin_amdgcn_sched_barrier(0)
#define LGKM(N)                                              \
  do {                                                       \
    asm volatile("s_waitcnt lgkmcnt(" #N ")" ::: "memory");  \
    SBAR0();                                                 \
  } while (0)
#define VMW(N)                                               \
  do {                                                       \
    asm volatile("s_waitcnt vmcnt(" #N ")" ::: "memory");    \
    SBAR0();                                                 \
  } while (0)
#define BARRIER()                 \
  do {                            \
    __builtin_amdgcn_s_barrier(); \
    SBAR0();                      \
  } while (0)

// out[b,d] = sum_l bias[l,d]  (clears 0xAA poison deterministically)
__global__ __launch_bounds__(256) void bias_init_kernel(
    const float* __restrict__ bias, const int* __restrict__ lidx,
    float* __restrict__ out) {
  int n = lidx[0] + 1;
  int i = blockIdx.x * 256 + threadIdx.x;
  if (i >= NB * ND) return;
  int d = i % ND;
  float s = 0.f;
  for (int l = 0; l < n; ++l) s += bias[l * ND + d];
  out[i] = s;
}

// W[l][f][d] fp32 -> Wt[l][d][f] bf16 (R12/R13-verified, ~48us)
__global__ __launch_bounds__(256) void wt_kernel(
    const float* __restrict__ W, unsigned short* __restrict__ wt) {
  __shared__ float t[64][65];
  const int l = blockIdx.z, f0 = blockIdx.x * 64, d0 = blockIdx.y * 64;
  const int tid = threadIdx.x;
  const int fr = tid >> 4;
  const int dc4 = (tid & 15) * 4;
  const float* src = W + ((size_t)l * NF + f0 + fr) * ND + d0 + dc4;
#pragma unroll
  for (int i = 0; i < 4; ++i) {
    float4 v = *(const float4*)(src + (size_t)16 * i * ND);
    t[fr + 16 * i][dc4 + 0] = v.x;
    t[fr + 16 * i][dc4 + 1] = v.y;
    t[fr + 16 * i][dc4 + 2] = v.z;
    t[fr + 16 * i][dc4 + 3] = v.w;
  }
  __syncthreads();
  const int dr = tid >> 4;
  const int fc4 = (tid & 15) * 4;
  unsigned short* dst = wt + ((size_t)l * ND + d0 + dr) * NF + f0 + fc4;
#pragma unroll
  for (int i = 0; i < 4; ++i) {
    bf16x4 h;
    h[0] = (__bf16)t[fc4 + 0][dr + 16 * i];
    h[1] = (__bf16)t[fc4 + 1][dr + 16 * i];
    h[2] = (__bf16)t[fc4 + 2][dr + 16 * i];
    h[3] = (__bf16)t[fc4 + 3][dr + 16 * i];
    *(bf16x4*)(dst + (size_t)16 * i * NF) = h;
  }
}

// ---------------- main GEMM: m201-faithful sandwich ----------------
// 256x192, 8 waves (4m x 2n), BK=64, split-K x2.
// A: fp32 reg-stage fused (globals issued P1, cvt+ds_write P3), LDS dbuf.
// B: bf16 W^T via global_load_lds, TRI-buffer, issued at P2 for t+2;
//    tile-boundary wait = counted vmcnt(3) (never 0 mid-loop).
// Each phase: {ds_read frags | stage issue} -> BAR -> lgkm0 -> setprio
// 16-MFMA -> BAR.  Issue-before-barrier / wait-after-barrier lets waves
// drain the LDS queue staggered: early waves MFMA while late waves' reads
// are served (the m201 overlap mechanism).
__global__ __launch_bounds__(512, 2) void gemm_sw(
    const float* __restrict__ acts, const unsigned short* __restrict__ wt,
    const int* __restrict__ lidx, float* __restrict__ out, int nwg) {
  extern __shared__ char cbuf[];  // LDS_TOTAL

  // by-fastest decode + XCD swizzle (R8: FETCH 1.27GB -> 405MB)
  const int chunk = nwg >> 3;  // 96
  const int swz = (blockIdx.x & 7) * chunk + (blockIdx.x >> 3);
  const int by = swz & 3;  // id = by + 4*(m + 8*(ks + 2*l))
  int rem = swz >> 2;
  const int m = rem & 7; rem >>= 3;
  const int ks = rem & 1; rem >>= 1;
  const int l = rem;
  if (l > lidx[0]) return;  // uniform exit before any barrier

  const int brow = m * BM;
  const int ncol = by * BN;
  const int k0 = ks * KCH;

  const int tid = threadIdx.x;
  const int lane = tid & 63;
  const int wid = tid >> 6;          // 8 waves: 4m x 2n
  const int wrow = (wid >> 1) * 64;  // 0,64,128,192
  const int wcol = (wid & 1) * 96;   // 0,96

  f32x4 acc[4][6];
#pragma unroll
  for (int i = 0; i < 4; ++i)
#pragma unroll
    for (int j = 0; j < 6; ++j) acc[i][j] = (f32x4){0.f, 0.f, 0.f, 0.f};

  // A reg-staging: thread -> (row = tid>>3 (+64 per p), 8 consecutive k)
  const int s_arow = tid >> 3;
  const int s_ak = (tid & 7) * 8;
  const float* Aptr =
      acts + (size_t)l * NB * NF + (size_t)(brow + s_arow) * NF + k0 + s_ak;
  float4 av[4][2];

  // B DMA (R13-proven): wave w, instr j covers rows r0=8*(3w+j); lane ->
  // row r0+(lane>>3), slot lane&7; global k-block = slot ^ fswz(row).
  const unsigned short* bSrc[3];
  int bDst[3];
#pragma unroll
  for (int j = 0; j < 3; ++j) {
    const int r0 = 8 * (3 * wid + j);
    const int r = r0 + (lane >> 3);
    const int ksl = (lane & 7) ^ fswz(r);
    bSrc[j] = wt + ((size_t)l * ND + ncol + r) * NF + k0 + ksl * 8;
    bDst[j] = r0 * 128;
  }

  auto ALOADS = [&](int kb) {
#pragma unroll
    for (int p = 0; p < 4; ++p) {
      av[p][0] = *(const float4*)(Aptr + (size_t)(64 * p) * NF + kb);
      av[p][1] = *(const float4*)(Aptr + (size_t)(64 * p) * NF + kb + 4);
    }
  };
  auto DMA_B = [&](int t) {
    char* b = cbuf + BBUF_OFF + (size_t)(t % 3) * B_BYTES;
#pragma unroll
    for (int j = 0; j < 3; ++j)
      async_ld16(b + bDst[j], bSrc[j] + (size_t)t * BK);
  };
  auto ASTORE = [&](char* cA_) {  // cvt + swizzled ds_write (reg-dep on av)
#pragma unroll
    for (int p = 0; p < 4; ++p) {
      bf16x8 h;
      h[0] = (__bf16)av[p][0].x; h[1] = (__bf16)av[p][0].y;
      h[2] = (__bf16)av[p][0].z; h[3] = (__bf16)av[p][0].w;
      h[4] = (__bf16)av[p][1].x; h[5] = (__bf16)av[p][1].y;
      h[6] = (__bf16)av[p][1].z; h[7] = (__bf16)av[p][1].w;
      *(bf16x8*)lds_addr(cA_, s_arow + 64 * p, s_ak) = h;
    }
  };

#define BF_READ(dst, P)                                                   \
  _Pragma("unroll") for (int ni = 0; ni < 2; ++ni)                        \
    _Pragma("unroll") for (int s = 0; s < 2; ++s)                         \
      dst[ni][s] = *(const bf16x8*)lds_addr(                              \
          rB, wcol + (2 * (P) + ni) * 16 + (lane & 15),                   \
          s * 32 + (lane >> 4) * 8);

#define MFMA16(bf, P)                                                     \
  __builtin_amdgcn_s_setprio(1);                                          \
  _Pragma("unroll") for (int s = 0; s < 2; ++s)                           \
    _Pragma("unroll") for (int mi = 0; mi < 4; ++mi)                      \
      _Pragma("unroll") for (int ni = 0; ni < 2; ++ni)                    \
        acc[mi][2 * (P) + ni] = __builtin_amdgcn_mfma_f32_16x16x32_bf16(  \
            aF[mi][s], bf[ni][s], acc[mi][2 * (P) + ni], 0, 0, 0);        \
  __builtin_amdgcn_s_setprio(0);                                          \
  SBAR0();

  // ---- prologue: tile 0 into A-buf0/B-buf0; B tile 1 DMA in flight ----
  ALOADS(0);
  ASTORE(cbuf);  // reg-dep waits own av (startup only)
  DMA_B(0);
  DMA_B(1);
  VMW(0);
  LGKM(0);
  BARRIER();

  for (int t = 0; t < NTIL; ++t) {
    char* rA = cbuf + (size_t)(t & 1) * A_BYTES;
    char* rB = cbuf + BBUF_OFF + (size_t)(t % 3) * B_BYTES;
    char* wA = cbuf + (size_t)((t + 1) & 1) * A_BYTES;
    const bool more1 = (t + 1 < NTIL);
    const bool more2 = (t + 2 < NTIL);

    // ===== P1: {aF + bF0 reads | issue A-globals(t+1)} -> 16 MFMA =====
    bf16x8 aF[4][2];
#pragma unroll
    for (int mi = 0; mi < 4; ++mi)
#pragma unroll
      for (int s = 0; s < 2; ++s)
        aF[mi][s] = *(const bf16x8*)lds_addr(
            rA, wrow + mi * 16 + (lane & 15), s * 32 + (lane >> 4) * 8);
    {
      bf16x8 bF[2][2];
      BF_READ(bF, 0)
      if (more1) ALOADS((t + 1) * BK);
      BARRIER();
      LGKM(0);
      MFMA16(bF, 0)
      BARRIER();
    }

    // ===== P2: {bF1 reads | issue B-DMA(t+2)} -> 16 MFMA =====
    {
      bf16x8 bF[2][2];
      BF_READ(bF, 1)
      if (more2) DMA_B(t + 2);
      BARRIER();
      LGKM(0);
      MFMA16(bF, 1)
      BARRIER();
    }

    // ===== P3: {bF2 reads | cvt+write A(t+1)} -> 16 MFMA =====
    {
      bf16x8 bF[2][2];
      BF_READ(bF, 2)
      if (more1) ASTORE(wA);  // auto-counted vmcnt via reg-dep on av
      BARRIER();
      LGKM(0);  // drains my bF reads AND my A ds_writes
      MFMA16(bF, 2)
      BARRIER();
    }

    // ===== boundary: counted DMA wait (3 newest = B(t+2) still fly) =====
    if (more2) { VMW(3); } else { VMW(0); }
    BARRIER();
  }

#undef BF_READ
#undef MFMA16

  // ---- epilogue: atomic accumulate (24 blocks collide: 12L x 2K) ----
  // C/D layout (m89-verified): col = lane&15, row = (lane>>4)*4 + j
  const int orow = brow + wrow + ((lane >> 4) << 2);
  const int ocol = ncol + wcol + (lane & 15);
#pragma unroll
  for (int mi = 0; mi < 4; ++mi)
#pragma unroll
    for (int ni = 0; ni < 6; ++ni)
#pragma unroll
      for (int j = 0; j < 4; ++j)
        atomicAdd(out + (size_t)(orow + mi * 16 + j) * ND + (ocol + ni * 16),
                  acc[mi][ni][j]);
}

// ---------------- fallback (ws too small): R8 fused kernel ----------------
#define F_BUF (A_BYTES + B_BYTES)
__global__ __launch_bounds__(512, 2) void gemm_fused(
    const float* __restrict__ acts, const float* __restrict__ W,
    const int* __restrict__ lidx, float* __restrict__ out, int nwg) {
  extern __shared__ char cbuf[];
  const int chunk = nwg >> 3;
  const int swz = (blockIdx.x & 7) * chunk + (blockIdx.x >> 3);
  const int by = swz & 3;
  int rem = swz >> 2;
  const int m = rem & 7; rem >>= 3;
  const int ks = rem & 1; rem >>= 1;
  const int l = rem;
  if (l > lidx[0]) return;
  const int brow = m * BM, ncol = by * BN, k0 = ks * KCH;
  const int tid = threadIdx.x, lane = tid & 63, wid = tid >> 6;
  const int wrow = (wid >> 1) * 64, wcol = (wid & 1) * 96;
  f32x4 acc[4][6];
#pragma unroll
  for (int i = 0; i < 4; ++i)
#pragma unroll
    for (int j = 0; j < 6; ++j) acc[i][j] = (f32x4){0.f, 0.f, 0.f, 0.f};
  const int s_arow = tid >> 3, s_ak = (tid & 7) * 8;
  const bool bstage = tid < 384;
  const int s_bd = (tid % 48) * 4, s_bk = (tid / 48) * 8;
  const float* Aptr =
      acts + (size_t)l * NB * NF + (size_t)(brow + s_arow) * NF + k0 + s_ak;
  const float* Bptr =
      W + (size_t)l * NF * ND + (size_t)(k0 + s_bk) * ND + (ncol + s_bd);
  float4 av[4][2]; float4 bv[8];
  auto LOADS = [&](int kb) {
#pragma unroll
    for (int p = 0; p < 4; ++p) {
      av[p][0] = *(const float4*)(Aptr + (size_t)(64 * p) * NF + kb);
      av[p][1] = *(const float4*)(Aptr + (size_t)(64 * p) * NF + kb + 4);
    }
    if (bstage) {
#pragma unroll
      for (int j = 0; j < 8; ++j)
        bv[j] = *(const float4*)(Bptr + (size_t)(kb + j) * ND);
    }
  };
  auto STORE = [&](char* cA_, char* cB_) {
#pragma unroll
    for (int p = 0; p < 4; ++p) {
      bf16x8 h;
      h[0] = (__bf16)av[p][0].x; h[1] = (__bf16)av[p][0].y;
      h[2] = (__bf16)av[p][0].z; h[3] = (__bf16)av[p][0].w;
      h[4] = (__bf16)av[p][1].x; h[5] = (__bf16)av[p][1].y;
      h[6] = (__bf16)av[p][1].z; h[7] = (__bf16)av[p][1].w;
      *(bf16x8*)lds_addr(cA_, s_arow + 64 * p, s_ak) = h;
    }
    if (bstage) {
#pragma unroll
      for (int dd = 0; dd < 4; ++dd) {
        bf16x8 h;
#pragma unroll
        for (int j = 0; j < 8; ++j) h[j] = (__bf16)bv[j][dd];
        *(bf16x8*)lds_addr(cB_, s_bd + dd, s_bk) = h;
      }
    }
  };
  LOADS(0);
  STORE(cbuf, cbuf + A_BYTES);
  for (int t = 0; t < NTIL; ++t) {
    const int cur = t & 1;
    char* rA = cbuf + (size_t)cur * F_BUF;
    char* rB = rA + A_BYTES;
    char* wA = cbuf + (size_t)(cur ^ 1) * F_BUF;
    char* wB = wA + A_BYTES;
    LGKM(0);
    BARRIER();
    if (t + 1 < NTIL) LOADS((t + 1) * BK);
    SBAR0();
    bf16x8 aF[4][2];
#pragma unroll
    for (int mi = 0; mi < 4; ++mi)
#pragma unroll
      for (int s = 0; s < 2; ++s)
        aF[mi][s] = *(const bf16x8*)lds_addr(
            rA, wrow + mi * 16 + (lane & 15), s * 32 + (lane >> 4) * 8);
#pragma unroll
    for (int p = 0; p < 3; ++p) {
      bf16x8 bF[2][2];
#pragma unroll
      for (int ni = 0; ni < 2; ++ni)
#pragma unroll
        for (int s = 0; s < 2; ++s)
          bF[ni][s] = *(const bf16x8*)lds_addr(
              rB, wcol + (2 * p + ni) * 16 + (lane & 15),
              s * 32 + (lane >> 4) * 8);
      LGKM(0);
      __builtin_amdgcn_s_setprio(1);
#pragma unroll
      for (int s = 0; s < 2; ++s)
#pragma unroll
        for (int mi = 0; mi < 4; ++mi)
#pragma unroll
          for (int ni = 0; ni < 2; ++ni)
            acc[mi][2 * p + ni] = __builtin_amdgcn_mfma_f32_16x16x32_bf16(
                aF[mi][s], bF[ni][s], acc[mi][2 * p + ni], 0, 0, 0);
      __builtin_amdgcn_s_setprio(0);
      SBAR0();
    }
    if (t + 1 < NTIL) STORE(wA, wB);
  }
  const int orow = brow + wrow + ((lane >> 4) << 2);
  const int ocol = ncol + wcol + (lane & 15);
#pragma unroll
  for (int mi = 0; mi < 4; ++mi)
#pragma unroll
    for (int ni = 0; ni < 6; ++ni)
#pragma unroll
      for (int j = 0; j < 4; ++j)
        atomicAdd(out + (size_t)(orow + mi * 16 + j) * ND + (ocol + ni * 16),
                  acc[mi][ni][j]);
}

extern "C" void kernel_launch(void* const* d_in, const int* in_sizes, int n_in,
                              void* d_out, int out_size, void* d_ws, size_t ws_size,
                              hipStream_t stream) {
  const float* acts = (const float*)d_in[0];
  const float* W    = (const float*)d_in[1];
  const float* bias = (const float*)d_in[2];
  const int*   lidx = (const int*)d_in[3];
  float* out = (float*)d_out;

  const int L = in_sizes[0] / (NB * NF);               // 12
  const int nwg = (ND / BN) * (NB / BM) * SPLITK * L;  // 768 = 3 x 256 CUs
  const size_t wsNeed = (size_t)L * NF * ND * 2;       // 113 MB bf16 W^T

  bias_init_kernel<<<dim3((NB * ND + 255) / 256), 256, 0, stream>>>(bias, lidx, out);

  if (ws_size >= wsNeed) {
    unsigned short* wsB = (unsigned short*)d_ws;
    wt_kernel<<<dim3(NF / 64, ND / 64, L), 256, 0, stream>>>(W, wsB);
    hipFuncSetAttribute((const void*)gemm_sw,
                        hipFuncAttributeMaxDynamicSharedMemorySize, LDS_TOTAL);
    gemm_sw<<<dim3(nwg), 512, LDS_TOTAL, stream>>>(acts, wsB, lidx, out, nwg);
  } else {
    hipFuncSetAttribute((const void*)gemm_fused,
                        hipFuncAttributeMaxDynamicSharedMemorySize, 2 * F_BUF);
    gemm_fused<<<dim3(nwg), 512, 2 * F_BUF, stream>>>(acts, W, lidx, out, nwg);
  }
}